// Round 6
// baseline (1861.729 us; speedup 1.0000x reference)
//
#include <hip/hip_runtime.h>
#include <hip/hip_fp16.h>
#include <math.h>

typedef _Float16 half8_t __attribute__((ext_vector_type(8)));
typedef float f32x4 __attribute__((ext_vector_type(4)));

struct __align__(16) h2x4 { __half2 a, b, c, d; };

// Edge access: flag=1 -> int64 storage, flag=0 -> int32.
__device__ inline int edge_src(const int* ew, int f, int e, int E) {
    return f ? ew[2 * e] : ew[e];
}
__device__ inline int edge_dst(const int* ew, int f, int e, int E) {
    return f ? ew[2 * E + 2 * e] : ew[E + e];
}

// ---------------- edge dtype sniff ----------------
__global__ void k_detect(const int* __restrict__ ew, int* __restrict__ flag) {
    __shared__ int nz;
    if (threadIdx.x == 0) nz = 0;
    __syncthreads();
    int a = ew[2 * threadIdx.x + 1];
    int b = ew[512 + 2 * threadIdx.x + 1];
    if (a | b) atomicAdd(&nz, 1);
    __syncthreads();
    if (threadIdx.x == 0) *flag = (nz == 0) ? 1 : 0;
}

// ---------------- bucketed CSR build (buckets of 256 dst nodes, NB<=256) ----------------
__global__ __launch_bounds__(256) void k_bhist(const int* __restrict__ ew,
                                               const int* __restrict__ flag,
                                               int* __restrict__ bsize,
                                               int E, int NB, int chunk) {
    __shared__ int hist[256];
    int t = threadIdx.x;
    hist[t] = 0;
    __syncthreads();
    int f = *flag;
    int c0 = blockIdx.x * chunk, c1 = min(E, c0 + chunk);
    for (int e = c0 + t; e < c1; e += 256)
        atomicAdd(&hist[edge_dst(ew, f, e, E) >> 8], 1);
    __syncthreads();
    if (t < NB && hist[t]) atomicAdd(&bsize[t], hist[t]);
}

__global__ __launch_bounds__(256) void k_bscan(const int* __restrict__ bsize,
                                               int* __restrict__ bbase,
                                               int* __restrict__ bcur, int NB) {
    __shared__ int buf[256];
    int t = threadIdx.x;
    int v = (t < NB) ? bsize[t] : 0;
    buf[t] = v;
    __syncthreads();
    int x = v;
    for (int off = 1; off < 256; off <<= 1) {
        int y = (t >= off) ? buf[t - off] : 0;
        __syncthreads();
        x += y;
        buf[t] = x;
        __syncthreads();
    }
    if (t <= NB) {
        int ex = (t < NB) ? (buf[t] - bsize[t]) : buf[NB ? NB - 1 : 0];
        bbase[t] = ex;
        if (t < NB) bcur[t] = ex;
    }
}

__global__ __launch_bounds__(256) void k_part(const int* __restrict__ ew,
                                              const int* __restrict__ flag,
                                              int* __restrict__ bcur,
                                              int2* __restrict__ be,
                                              int E, int NB, int chunk) {
    __shared__ int histL[256], baseL[256];
    int t = threadIdx.x;
    histL[t] = 0;
    __syncthreads();
    int f = *flag;
    int c0 = blockIdx.x * chunk, c1 = min(E, c0 + chunk);
    for (int e = c0 + t; e < c1; e += 256)
        atomicAdd(&histL[edge_dst(ew, f, e, E) >> 8], 1);
    __syncthreads();
    if (t < NB) {
        int h = histL[t];
        baseL[t] = h ? atomicAdd(&bcur[t], h) : 0;
    }
    __syncthreads();
    histL[t] = 0;
    __syncthreads();
    for (int e = c0 + t; e < c1; e += 256) {
        int s = edge_src(ew, f, e, E);
        int d = edge_dst(ew, f, e, E);
        int b = d >> 8;
        int off = baseL[b] + atomicAdd(&histL[b], 1);
        be[off] = make_int2(s, d);
    }
}

// per-bucket degree count (no global atomics)
__global__ __launch_bounds__(256) void k_bdeg(const int2* __restrict__ be,
                                              const int* __restrict__ bbase,
                                              int* __restrict__ deg, int N) {
    __shared__ int cnt[256];
    int t = threadIdx.x, b = blockIdx.x;
    cnt[t] = 0;
    __syncthreads();
    int p0 = bbase[b], p1 = bbase[b + 1];
    for (int p = p0 + t; p < p1; p += 256)
        atomicAdd(&cnt[be[p].y & 255], 1);
    __syncthreads();
    int i = (b << 8) + t;
    if (i < N) deg[i] = cnt[t];
}

// ---------------- scan deg -> rp ----------------
__global__ __launch_bounds__(1024) void k_scan1(const int* __restrict__ deg,
                                                int* __restrict__ rp,
                                                int* __restrict__ bsum, int N) {
    __shared__ int buf[1024];
    int t = threadIdx.x;
    int i = blockIdx.x * 1024 + t;
    int v = (i < N) ? deg[i] : 0;
    buf[t] = v;
    __syncthreads();
    int x = v;
    for (int off = 1; off < 1024; off <<= 1) {
        int y = (t >= off) ? buf[t - off] : 0;
        __syncthreads();
        x += y;
        buf[t] = x;
        __syncthreads();
    }
    if (i < N) rp[i] = x - v;
    if (t == 1023) bsum[blockIdx.x] = x;
}

__global__ void k_scan2(int* __restrict__ bsum, int* __restrict__ rp,
                        int nb, int N) {
    int lane = threadIdx.x;
    int v = (lane < nb) ? bsum[lane] : 0;
    int x = v;
    for (int off = 1; off < 64; off <<= 1) {
        int y = __shfl_up(x, off);
        if (lane >= off) x += y;
    }
    if (lane < nb) bsum[lane] = x - v;
    if (lane == 63) rp[N] = x;
}

__global__ void k_fixup(int* __restrict__ rp, const int* __restrict__ bsum,
                        const int* __restrict__ deg, float* __restrict__ dinv, int N) {
    int i = blockIdx.x * blockDim.x + threadIdx.x;
    if (i < N) {
        rp[i] += bsum[i >> 10];
        dinv[i] = rsqrtf((float)(deg[i] + 1));  // +1 self loop
    }
}

// fill col: one block per bucket; pack src (16b) | dst-low-byte (bits 16-23)
__global__ __launch_bounds__(256) void k_fillb(const int2* __restrict__ be,
                                               const int* __restrict__ bbase,
                                               const int* __restrict__ rp,
                                               int* __restrict__ col, int N) {
    __shared__ int cur[256];
    int t = threadIdx.x, b = blockIdx.x;
    int i = (b << 8) + t;
    cur[t] = (i < N) ? rp[i] : 0;
    __syncthreads();
    int p0 = bbase[b], p1 = bbase[b + 1];
    for (int p = p0 + t; p < p1; p += 256) {
        int2 e = be[p];
        int pos = atomicAdd(&cur[e.y & 255], 1);
        col[pos] = (e.x & 0xFFFF) | ((e.y & 0xFF) << 16);
    }
}

// ------- MFMA matmul: H = fp16( dinv[r] * act(X) @ W ), W f32->f16 staged in LDS -------
template <int D, bool FUSE, bool XF32>
__global__ __launch_bounds__(256) void k_mmf(const void* __restrict__ Xv,
                                             const float* __restrict__ W,
                                             __half* __restrict__ H,
                                             const float* __restrict__ dinv,
                                             const float* __restrict__ S,
                                             const float* __restrict__ g,
                                             const float* __restrict__ be_,
                                             int N, float invN) {
    constexpr int NF = D / 16;
    __shared__ _Float16 sW[4][NF][4][16][8];
    __shared__ float sAl[128], sBe[128];
    const int t = threadIdx.x;
    if (FUSE && t < 128) {
        float m = S[t] * invN;
        float var = fmaf(-m, m, S[128 + t] * invN);
        float al = g[t] * rsqrtf(var + 1e-5f);
        sAl[t] = al;
        sBe[t] = fmaf(-m, al, be_[t]);
    }
    for (int idx = t; idx < 128 * D / 4; idx += 256) {
        int k = idx / (D / 4);
        int n4 = (idx % (D / 4)) * 4;
        float4 w4 = reinterpret_cast<const float4*>(W)[idx];
        int kb = k >> 5, kg = (k >> 3) & 3, j = k & 7;
        const float* wp = &w4.x;
#pragma unroll
        for (int jj = 0; jj < 4; jj++) {
            int n = n4 + jj;
            sW[kb][n >> 4][kg][n & 15][j] = (_Float16)wp[jj];
        }
    }
    __syncthreads();

    const int l = t & 63;
    const int w = t >> 6;
    const int row_base = blockIdx.x * 64 + w * 16;
    const int m16 = l & 15, kg = l >> 4;

    f32x4 acc[NF];
#pragma unroll
    for (int nf = 0; nf < NF; nf++) acc[nf] = (f32x4){0.f, 0.f, 0.f, 0.f};

    int ra = row_base + m16;
    if (ra > N - 1) ra = N - 1;

#pragma unroll
    for (int kb = 0; kb < 4; kb++) {
        int kbase = kb * 32 + kg * 8;
        half8_t a;
        if (XF32) {
            const float* Xf = (const float*)Xv;
            float4 x0 = reinterpret_cast<const float4*>(Xf + (size_t)ra * 128 + kbase)[0];
            float4 x1 = reinterpret_cast<const float4*>(Xf + (size_t)ra * 128 + kbase)[1];
            a[0] = (_Float16)x0.x; a[1] = (_Float16)x0.y;
            a[2] = (_Float16)x0.z; a[3] = (_Float16)x0.w;
            a[4] = (_Float16)x1.x; a[5] = (_Float16)x1.y;
            a[6] = (_Float16)x1.z; a[7] = (_Float16)x1.w;
        } else {
            const __half* Xh = (const __half*)Xv;
            a = *reinterpret_cast<const half8_t*>(Xh + (size_t)ra * 128 + kbase);
            if (FUSE) {
                float4 al0 = *reinterpret_cast<const float4*>(&sAl[kbase]);
                float4 al1 = *reinterpret_cast<const float4*>(&sAl[kbase + 4]);
                float4 be0 = *reinterpret_cast<const float4*>(&sBe[kbase]);
                float4 be1 = *reinterpret_cast<const float4*>(&sBe[kbase + 4]);
                const float* alp0 = &al0.x; const float* alp1 = &al1.x;
                const float* bep0 = &be0.x; const float* bep1 = &be1.x;
#pragma unroll
                for (int j = 0; j < 4; j++)
                    a[j] = (_Float16)fmaxf(0.f, fmaf(alp0[j], (float)a[j], bep0[j]));
#pragma unroll
                for (int j = 0; j < 4; j++)
                    a[4 + j] = (_Float16)fmaxf(0.f, fmaf(alp1[j], (float)a[4 + j], bep1[j]));
            }
        }
#pragma unroll
        for (int nf = 0; nf < NF; nf++) {
            half8_t b = *reinterpret_cast<const half8_t*>(&sW[kb][nf][kg][m16][0]);
            acc[nf] = __builtin_amdgcn_mfma_f32_16x16x32_f16(a, b, acc[nf], 0, 0, 0);
        }
    }

    float dv[4];
    int rbase = row_base + kg * 4;
#pragma unroll
    for (int r = 0; r < 4; r++)
        dv[r] = (rbase + r < N) ? dinv[rbase + r] : 0.f;
#pragma unroll
    for (int nf = 0; nf < NF; nf++) {
#pragma unroll
        for (int r = 0; r < 4; r++) {
            int gr = rbase + r;
            if (gr < N)
                H[(size_t)gr * D + nf * 16 + m16] = __float2half(acc[nf][r] * dv[r]);
        }
    }
}

// ------- edge-parallel agg D=128: 64 dst nodes/block, LDS f32 accumulators -------
__global__ __launch_bounds__(1024) void k_aggE128(const __half* __restrict__ Hs,
                                                  const int* __restrict__ rp,
                                                  const int* __restrict__ col,
                                                  const float* __restrict__ dinv,
                                                  const float* __restrict__ bias,
                                                  __half* __restrict__ out, int N) {
    __shared__ float acc[64 * 128];
    const int t = threadIdx.x;
    const int i0 = blockIdx.x * 64;
    const int iend = min(i0 + 64, N);
    for (int idx = t; idx < 64 * 128; idx += 1024) acc[idx] = 0.f;
    __syncthreads();

    const int p0 = rp[i0], p1 = rp[iend];
    const int lane = t & 63, wv = t >> 6;
    const int len = p1 - p0;
    const int per = (len + 15) >> 4;
    int e0 = min(p0 + wv * per, p1);
    int e1 = min(e0 + per, p1);

    int e = e0;
    for (; e + 8 <= e1; e += 8) {
        int w8[8];
        __half va[8], vb[8];
#pragma unroll
        for (int u = 0; u < 8; u++) w8[u] = col[e + u];
#pragma unroll
        for (int u = 0; u < 8; u++) {
            int s = w8[u] & 0xFFFF;
            va[u] = Hs[(size_t)s * 128 + lane];
            vb[u] = Hs[(size_t)s * 128 + 64 + lane];
        }
#pragma unroll
        for (int u = 0; u < 8; u++) {
            int d = (w8[u] >> 16) & 63;
            atomicAdd(&acc[d * 128 + lane], __half2float(va[u]));
            atomicAdd(&acc[d * 128 + 64 + lane], __half2float(vb[u]));
        }
    }
    for (; e < e1; e++) {
        int w = col[e];
        int s = w & 0xFFFF, d = (w >> 16) & 63;
        atomicAdd(&acc[d * 128 + lane], __half2float(Hs[(size_t)s * 128 + lane]));
        atomicAdd(&acc[d * 128 + 64 + lane], __half2float(Hs[(size_t)s * 128 + 64 + lane]));
    }
    __syncthreads();

    // epilogue: out[i] = fp16( di * (acc + Hs[i]) + bias )
    int node = t >> 4;
    int fo = (t & 15) * 8;
    int i = i0 + node;
    if (i < N) {
        float di = dinv[i];
        half8_t self = *reinterpret_cast<const half8_t*>(Hs + (size_t)i * 128 + fo);
        __half2 o[4];
#pragma unroll
        for (int jp = 0; jp < 4; jp++) {
            float lo = fmaf(di, acc[node * 128 + fo + 2 * jp]     + (float)self[2 * jp],     bias[fo + 2 * jp]);
            float hi = fmaf(di, acc[node * 128 + fo + 2 * jp + 1] + (float)self[2 * jp + 1], bias[fo + 2 * jp + 1]);
            o[jp] = __floats2half2_rn(lo, hi);
        }
        *reinterpret_cast<h2x4*>(out + (size_t)i * 128 + fo) = *(h2x4*)o;
    }
}

// ------- edge-parallel agg D=64: 128 dst nodes/block, f32 output -------
__global__ __launch_bounds__(1024) void k_aggE64(const __half* __restrict__ Hs,
                                                 const int* __restrict__ rp,
                                                 const int* __restrict__ col,
                                                 const float* __restrict__ dinv,
                                                 const float* __restrict__ bias,
                                                 float* __restrict__ out, int N) {
    __shared__ float acc[128 * 64];
    const int t = threadIdx.x;
    const int i0 = blockIdx.x * 128;
    const int iend = min(i0 + 128, N);
    for (int idx = t; idx < 128 * 64; idx += 1024) acc[idx] = 0.f;
    __syncthreads();

    const int p0 = rp[i0], p1 = rp[iend];
    const int lane = t & 63, wv = t >> 6;
    const int len = p1 - p0;
    const int per = (len + 15) >> 4;
    int e0 = min(p0 + wv * per, p1);
    int e1 = min(e0 + per, p1);

    int e = e0;
    for (; e + 8 <= e1; e += 8) {
        int w8[8];
        __half va[8];
#pragma unroll
        for (int u = 0; u < 8; u++) w8[u] = col[e + u];
#pragma unroll
        for (int u = 0; u < 8; u++) {
            int s = w8[u] & 0xFFFF;
            va[u] = Hs[(size_t)s * 64 + lane];
        }
#pragma unroll
        for (int u = 0; u < 8; u++) {
            int d = (w8[u] >> 16) & 127;
            atomicAdd(&acc[d * 64 + lane], __half2float(va[u]));
        }
    }
    for (; e < e1; e++) {
        int w = col[e];
        int s = w & 0xFFFF, d = (w >> 16) & 127;
        atomicAdd(&acc[d * 64 + lane], __half2float(Hs[(size_t)s * 64 + lane]));
    }
    __syncthreads();

    int node = t >> 3;
    int fo = (t & 7) * 8;
    int i = i0 + node;
    if (i < N) {
        float di = dinv[i];
        half8_t self = *reinterpret_cast<const half8_t*>(Hs + (size_t)i * 64 + fo);
        float4 o0, o1;
        float* op = &o0.x;
#pragma unroll
        for (int j = 0; j < 4; j++)
            op[j] = fmaf(di, acc[node * 64 + fo + j] + (float)self[j], bias[fo + j]);
        float* op1 = &o1.x;
#pragma unroll
        for (int j = 0; j < 4; j++)
            op1[j] = fmaf(di, acc[node * 64 + fo + 4 + j] + (float)self[4 + j], bias[fo + 4 + j]);
        reinterpret_cast<float4*>(out + (size_t)i * 64 + fo)[0] = o0;
        reinterpret_cast<float4*>(out + (size_t)i * 64 + fo + 4)[0] = o1;
    }
}

// ---------------- BN stats over f16 t ----------------
__global__ __launch_bounds__(256) void k_stats(const __half2* __restrict__ X2,
                                               float* __restrict__ S, int N) {
    int cp = threadIdx.x & 63;
    int hr = threadIdx.x >> 6;
    int rend = min(N, (int)(blockIdx.x + 1) * 256);
    float2 s = make_float2(0.f, 0.f), q = make_float2(0.f, 0.f);
    for (int r = blockIdx.x * 256 + hr; r < rend; r += 4) {
        float2 v = __half22float2(X2[(size_t)r * 64 + cp]);
        s.x += v.x; s.y += v.y;
        q.x += v.x * v.x; q.y += v.y * v.y;
    }
    __shared__ float ls[4][64][2], lq[4][64][2];
    ls[hr][cp][0] = s.x; ls[hr][cp][1] = s.y;
    lq[hr][cp][0] = q.x; lq[hr][cp][1] = q.y;
    __syncthreads();
    if (hr == 0) {
#pragma unroll
        for (int j = 1; j < 4; j++) {
            s.x += ls[j][cp][0]; s.y += ls[j][cp][1];
            q.x += lq[j][cp][0]; q.y += lq[j][cp][1];
        }
        atomicAdd(&S[2 * cp], s.x);
        atomicAdd(&S[2 * cp + 1], s.y);
        atomicAdd(&S[128 + 2 * cp], q.x);
        atomicAdd(&S[128 + 2 * cp + 1], q.y);
    }
}

// ---------------- launch ----------------
extern "C" void kernel_launch(void* const* d_in, const int* in_sizes, int n_in,
                              void* d_out, int out_size, void* d_ws, size_t ws_size,
                              hipStream_t stream) {
    const float* x   = (const float*)d_in[0];
    const int*   ew  = (const int*)d_in[1];
    const float* W1  = (const float*)d_in[2];
    const float* b1  = (const float*)d_in[3];
    const float* g1  = (const float*)d_in[4];
    const float* be1 = (const float*)d_in[5];
    const float* W2  = (const float*)d_in[6];
    const float* b2  = (const float*)d_in[7];
    const float* g2  = (const float*)d_in[8];
    const float* be2 = (const float*)d_in[9];
    const float* W3  = (const float*)d_in[10];
    const float* b3  = (const float*)d_in[11];
    const int N = in_sizes[0] / 128;
    const int E = in_sizes[1] / 2;
    const int NB = (N + 255) >> 8;

    char* w = (char*)d_ws;
    size_t off = 0;
    auto alloc = [&](size_t bytes) -> char* {
        char* p = w + off;
        off = (off + bytes + 255) & ~(size_t)255;
        return p;
    };
    int*    col   = (int*)alloc((size_t)E * 4);
    int2*   be    = (int2*)alloc((size_t)E * 8);
    int*    deg   = (int*)alloc((size_t)N * 4);
    int*    rp    = (int*)alloc((size_t)(N + 1) * 4);
    float*  dinv  = (float*)alloc((size_t)N * 4);
    float*  S1    = (float*)alloc(1024);
    float*  S2    = (float*)alloc(1024);
    int*    flag  = (int*)alloc(256);
    int*    bsum  = (int*)alloc(64 * 4);
    int*    bsize = (int*)alloc(257 * 4);
    int*    bbase = (int*)alloc(257 * 4);
    int*    bcur  = (int*)alloc(257 * 4);
    __half* h     = (__half*)alloc((size_t)N * 128 * 2);
    __half* t     = (__half*)alloc((size_t)N * 128 * 2);
    (void)ws_size; (void)n_in; (void)out_size;

    const int gN = (N + 255) / 256;
    const int gM = (N + 63) / 64;
    const int gE128 = (N + 63) / 64;
    const int gE64 = (N + 127) / 128;
    const int gS = (N + 255) / 256;
    const int nb = (N + 1023) / 1024;
    const int PB = 128;
    const int chunk = (E + PB - 1) / PB;
    const float invN = 1.0f / (float)N;

    hipMemsetAsync(bsize, 0, 257 * 4, stream);
    hipMemsetAsync(S1, 0, 1024, stream);
    hipMemsetAsync(S2, 0, 1024, stream);
    k_detect<<<1, 256, 0, stream>>>(ew, flag);
    k_bhist<<<PB, 256, 0, stream>>>(ew, flag, bsize, E, NB, chunk);
    k_bscan<<<1, 256, 0, stream>>>(bsize, bbase, bcur, NB);
    k_part<<<PB, 256, 0, stream>>>(ew, flag, bcur, be, E, NB, chunk);
    k_bdeg<<<NB, 256, 0, stream>>>(be, bbase, deg, N);
    k_scan1<<<nb, 1024, 0, stream>>>(deg, rp, bsum, N);
    k_scan2<<<1, 64, 0, stream>>>(bsum, rp, nb, N);
    k_fixup<<<gN, 256, 0, stream>>>(rp, bsum, deg, dinv, N);
    k_fillb<<<NB, 256, 0, stream>>>(be, bbase, rp, col, N);

    // layer 1
    k_mmf<128, false, true><<<gM, 256, 0, stream>>>(x, W1, h, dinv, S1, g1, be1, N, invN);
    k_aggE128<<<gE128, 1024, 0, stream>>>(h, rp, col, dinv, b1, t, N);
    k_stats<<<gS, 256, 0, stream>>>((const __half2*)t, S1, N);

    // layer 2 (BN1+ReLU fused into A-fragment load)
    k_mmf<128, true, false><<<gM, 256, 0, stream>>>(t, W2, h, dinv, S1, g1, be1, N, invN);
    k_aggE128<<<gE128, 1024, 0, stream>>>(h, rp, col, dinv, b2, t, N);
    k_stats<<<gS, 256, 0, stream>>>((const __half2*)t, S2, N);

    // layer 3 (BN2+ReLU fused, D_OUT = 64, straight to d_out)
    k_mmf<64, true, false><<<gM, 256, 0, stream>>>(t, W3, h, dinv, S2, g2, be2, N, invN);
    k_aggE64<<<gE64, 1024, 0, stream>>>(h, rp, col, dinv, b3, (float*)d_out, N);
}

// Round 7
// 258.021 us; speedup vs baseline: 7.2154x; 7.2154x over previous
//
#include <hip/hip_runtime.h>
#include <hip/hip_fp16.h>
#include <math.h>

typedef _Float16 half8_t __attribute__((ext_vector_type(8)));
typedef float f32x4 __attribute__((ext_vector_type(4)));

struct __align__(16) h2x4 { __half2 a, b, c, d; };

// Edge access: flag=1 -> int64 storage, flag=0 -> int32.
__device__ inline int edge_src(const int* ew, int f, int e, int E) {
    return f ? ew[2 * e] : ew[e];
}
__device__ inline int edge_dst(const int* ew, int f, int e, int E) {
    return f ? ew[2 * E + 2 * e] : ew[E + e];
}

// ---------------- edge dtype sniff ----------------
__global__ void k_detect(const int* __restrict__ ew, int* __restrict__ flag) {
    __shared__ int nz;
    if (threadIdx.x == 0) nz = 0;
    __syncthreads();
    int a = ew[2 * threadIdx.x + 1];
    int b = ew[512 + 2 * threadIdx.x + 1];
    if (a | b) atomicAdd(&nz, 1);
    __syncthreads();
    if (threadIdx.x == 0) *flag = (nz == 0) ? 1 : 0;
}

// ---------------- bucketed CSR build (buckets of 256 dst nodes, NB<=256) ----------------
__global__ __launch_bounds__(256) void k_bhist(const int* __restrict__ ew,
                                               const int* __restrict__ flag,
                                               int* __restrict__ bsize,
                                               int E, int NB, int chunk) {
    __shared__ int hist[256];
    int t = threadIdx.x;
    hist[t] = 0;
    __syncthreads();
    int f = *flag;
    int c0 = blockIdx.x * chunk, c1 = min(E, c0 + chunk);
    for (int e = c0 + t; e < c1; e += 256)
        atomicAdd(&hist[edge_dst(ew, f, e, E) >> 8], 1);
    __syncthreads();
    if (t < NB && hist[t]) atomicAdd(&bsize[t], hist[t]);
}

__global__ __launch_bounds__(256) void k_bscan(const int* __restrict__ bsize,
                                               int* __restrict__ bbase,
                                               int* __restrict__ bcur, int NB) {
    __shared__ int buf[256];
    int t = threadIdx.x;
    int v = (t < NB) ? bsize[t] : 0;
    buf[t] = v;
    __syncthreads();
    int x = v;
    for (int off = 1; off < 256; off <<= 1) {
        int y = (t >= off) ? buf[t - off] : 0;
        __syncthreads();
        x += y;
        buf[t] = x;
        __syncthreads();
    }
    if (t <= NB) {
        int ex = (t < NB) ? (buf[t] - bsize[t]) : buf[NB ? NB - 1 : 0];
        bbase[t] = ex;
        if (t < NB) bcur[t] = ex;
    }
}

__global__ __launch_bounds__(256) void k_part(const int* __restrict__ ew,
                                              const int* __restrict__ flag,
                                              int* __restrict__ bcur,
                                              int2* __restrict__ be,
                                              int E, int NB, int chunk) {
    __shared__ int histL[256], baseL[256];
    int t = threadIdx.x;
    histL[t] = 0;
    __syncthreads();
    int f = *flag;
    int c0 = blockIdx.x * chunk, c1 = min(E, c0 + chunk);
    for (int e = c0 + t; e < c1; e += 256)
        atomicAdd(&histL[edge_dst(ew, f, e, E) >> 8], 1);
    __syncthreads();
    if (t < NB) {
        int h = histL[t];
        baseL[t] = h ? atomicAdd(&bcur[t], h) : 0;
    }
    __syncthreads();
    histL[t] = 0;
    __syncthreads();
    for (int e = c0 + t; e < c1; e += 256) {
        int s = edge_src(ew, f, e, E);
        int d = edge_dst(ew, f, e, E);
        int b = d >> 8;
        int off = baseL[b] + atomicAdd(&histL[b], 1);
        be[off] = make_int2(s, d);
    }
}

// per-bucket degree count + in-block scan -> rp, dinv (replaces deg/scan1/scan2/fixup)
__global__ __launch_bounds__(256) void k_bdegscan(const int2* __restrict__ be,
                                                  const int* __restrict__ bbase,
                                                  int* __restrict__ rp,
                                                  float* __restrict__ dinv,
                                                  int N, int NB) {
    __shared__ int cnt[256];
    __shared__ int buf[256];
    int t = threadIdx.x, b = blockIdx.x;
    cnt[t] = 0;
    __syncthreads();
    int p0 = bbase[b], p1 = bbase[b + 1];
    for (int p = p0 + t; p < p1; p += 256)
        atomicAdd(&cnt[be[p].y & 255], 1);
    __syncthreads();
    int v = cnt[t];
    buf[t] = v;
    __syncthreads();
    int x = v;
    for (int off = 1; off < 256; off <<= 1) {
        int y = (t >= off) ? buf[t - off] : 0;
        __syncthreads();
        x += y;
        buf[t] = x;
        __syncthreads();
    }
    int i = (b << 8) + t;
    if (i < N) {
        rp[i] = bbase[b] + x - v;        // exclusive
        dinv[i] = rsqrtf((float)(v + 1)); // +1 self loop
    }
    if (b == NB - 1 && t == 255) rp[N] = bbase[b] + x;  // = E
}

// fill col: one block per bucket; pack src (16b) | dst-low-byte (bits 16-23)
__global__ __launch_bounds__(256) void k_fillb(const int2* __restrict__ be,
                                               const int* __restrict__ bbase,
                                               const int* __restrict__ rp,
                                               int* __restrict__ col, int N) {
    __shared__ int cur[256];
    int t = threadIdx.x, b = blockIdx.x;
    int i = (b << 8) + t;
    cur[t] = (i < N) ? rp[i] : 0;
    __syncthreads();
    int p0 = bbase[b], p1 = bbase[b + 1];
    for (int p = p0 + t; p < p1; p += 256) {
        int2 e = be[p];
        int pos = atomicAdd(&cur[e.y & 255], 1);
        col[pos] = (e.x & 0xFFFF) | ((e.y & 0xFF) << 16);
    }
}

// ------- MFMA matmul: H = fp16( dinv[r] * act(X) @ W ), W f32->f16 staged in LDS -------
template <int D, bool FUSE, bool XF32>
__global__ __launch_bounds__(256) void k_mmf(const void* __restrict__ Xv,
                                             const float* __restrict__ W,
                                             __half* __restrict__ H,
                                             const float* __restrict__ dinv,
                                             const float* __restrict__ S,
                                             const float* __restrict__ g,
                                             const float* __restrict__ be_,
                                             int N, float invN) {
    constexpr int NF = D / 16;
    __shared__ _Float16 sW[4][NF][4][16][8];
    __shared__ float sAl[128], sBe[128];
    const int t = threadIdx.x;
    if (FUSE && t < 128) {
        float m = S[t] * invN;
        float var = fmaf(-m, m, S[128 + t] * invN);
        float al = g[t] * rsqrtf(var + 1e-5f);
        sAl[t] = al;
        sBe[t] = fmaf(-m, al, be_[t]);
    }
    for (int idx = t; idx < 128 * D / 4; idx += 256) {
        int k = idx / (D / 4);
        int n4 = (idx % (D / 4)) * 4;
        float4 w4 = reinterpret_cast<const float4*>(W)[idx];
        int kb = k >> 5, kg = (k >> 3) & 3, j = k & 7;
        const float* wp = &w4.x;
#pragma unroll
        for (int jj = 0; jj < 4; jj++) {
            int n = n4 + jj;
            sW[kb][n >> 4][kg][n & 15][j] = (_Float16)wp[jj];
        }
    }
    __syncthreads();

    const int l = t & 63;
    const int w = t >> 6;
    const int row_base = blockIdx.x * 64 + w * 16;
    const int m16 = l & 15, kg = l >> 4;

    f32x4 acc[NF];
#pragma unroll
    for (int nf = 0; nf < NF; nf++) acc[nf] = (f32x4){0.f, 0.f, 0.f, 0.f};

    int ra = row_base + m16;
    if (ra > N - 1) ra = N - 1;

#pragma unroll
    for (int kb = 0; kb < 4; kb++) {
        int kbase = kb * 32 + kg * 8;
        half8_t a;
        if (XF32) {
            const float* Xf = (const float*)Xv;
            float4 x0 = reinterpret_cast<const float4*>(Xf + (size_t)ra * 128 + kbase)[0];
            float4 x1 = reinterpret_cast<const float4*>(Xf + (size_t)ra * 128 + kbase)[1];
            a[0] = (_Float16)x0.x; a[1] = (_Float16)x0.y;
            a[2] = (_Float16)x0.z; a[3] = (_Float16)x0.w;
            a[4] = (_Float16)x1.x; a[5] = (_Float16)x1.y;
            a[6] = (_Float16)x1.z; a[7] = (_Float16)x1.w;
        } else {
            const __half* Xh = (const __half*)Xv;
            a = *reinterpret_cast<const half8_t*>(Xh + (size_t)ra * 128 + kbase);
            if (FUSE) {
                float4 al0 = *reinterpret_cast<const float4*>(&sAl[kbase]);
                float4 al1 = *reinterpret_cast<const float4*>(&sAl[kbase + 4]);
                float4 be0 = *reinterpret_cast<const float4*>(&sBe[kbase]);
                float4 be1 = *reinterpret_cast<const float4*>(&sBe[kbase + 4]);
                const float* alp0 = &al0.x; const float* alp1 = &al1.x;
                const float* bep0 = &be0.x; const float* bep1 = &be1.x;
#pragma unroll
                for (int j = 0; j < 4; j++)
                    a[j] = (_Float16)fmaxf(0.f, fmaf(alp0[j], (float)a[j], bep0[j]));
#pragma unroll
                for (int j = 0; j < 4; j++)
                    a[4 + j] = (_Float16)fmaxf(0.f, fmaf(alp1[j], (float)a[4 + j], bep1[j]));
            }
        }
#pragma unroll
        for (int nf = 0; nf < NF; nf++) {
            half8_t b = *reinterpret_cast<const half8_t*>(&sW[kb][nf][kg][m16][0]);
            acc[nf] = __builtin_amdgcn_mfma_f32_16x16x32_f16(a, b, acc[nf], 0, 0, 0);
        }
    }

    float dv[4];
    int rbase = row_base + kg * 4;
#pragma unroll
    for (int r = 0; r < 4; r++)
        dv[r] = (rbase + r < N) ? dinv[rbase + r] : 0.f;
#pragma unroll
    for (int nf = 0; nf < NF; nf++) {
#pragma unroll
        for (int r = 0; r < 4; r++) {
            int gr = rbase + r;
            if (gr < N)
                H[(size_t)gr * D + nf * 16 + m16] = __float2half(acc[nf][r] * dv[r]);
        }
    }
}

// ------- agg D=128: one wave per node, predicated 16-wide batches (no serial tail) -------
__global__ __launch_bounds__(256) void k_agg128(const __half2* __restrict__ Hs,
                                                const int* __restrict__ rp,
                                                const int* __restrict__ col,
                                                const float* __restrict__ dinv,
                                                const float* __restrict__ bias,
                                                __half2* __restrict__ out, int N) {
    int wv = threadIdx.x >> 6, lane = threadIdx.x & 63;
    int i = blockIdx.x * 4 + wv;
    if (i >= N) return;
    int e0 = rp[i], e1 = rp[i + 1];
    float di = dinv[i];
    float2 a = __half22float2(Hs[(size_t)i * 64 + lane]);
    for (int e = e0; e < e1; e += 16) {
        float2 v[16];
#pragma unroll
        for (int u = 0; u < 16; u++) {
            int idx = e + u;
            bool ok = idx < e1;
            int s = col[ok ? idx : e0] & 0xFFFF;
            float2 f = __half22float2(Hs[(size_t)s * 64 + lane]);
            v[u].x = ok ? f.x : 0.f;
            v[u].y = ok ? f.y : 0.f;
        }
#pragma unroll
        for (int st = 1; st < 16; st <<= 1)
#pragma unroll
            for (int u = 0; u < 16; u += 2 * st) {
                v[u].x += v[u + st].x;
                v[u].y += v[u + st].y;
            }
        a.x += v[0].x;
        a.y += v[0].y;
    }
    float2 b = reinterpret_cast<const float2*>(bias)[lane];
    out[(size_t)i * 64 + lane] = __floats2half2_rn(fmaf(di, a.x, b.x), fmaf(di, a.y, b.y));
}

// ------- agg D=64: half-wave per node, predicated batches, f32 output -------
__global__ __launch_bounds__(256) void k_agg64(const __half2* __restrict__ Hs,
                                               const int* __restrict__ rp,
                                               const int* __restrict__ col,
                                               const float* __restrict__ dinv,
                                               const float* __restrict__ bias,
                                               float* __restrict__ out, int N) {
    int sub = threadIdx.x & 31;
    int i = blockIdx.x * 8 + (threadIdx.x >> 5);
    if (i >= N) return;
    int e0 = rp[i], e1 = rp[i + 1];
    float di = dinv[i];
    float2 a = __half22float2(Hs[(size_t)i * 32 + sub]);
    for (int e = e0; e < e1; e += 16) {
        float2 v[16];
#pragma unroll
        for (int u = 0; u < 16; u++) {
            int idx = e + u;
            bool ok = idx < e1;
            int s = col[ok ? idx : e0] & 0xFFFF;
            float2 f = __half22float2(Hs[(size_t)s * 32 + sub]);
            v[u].x = ok ? f.x : 0.f;
            v[u].y = ok ? f.y : 0.f;
        }
#pragma unroll
        for (int st = 1; st < 16; st <<= 1)
#pragma unroll
            for (int u = 0; u < 16; u += 2 * st) {
                v[u].x += v[u + st].x;
                v[u].y += v[u + st].y;
            }
        a.x += v[0].x;
        a.y += v[0].y;
    }
    float2 b = reinterpret_cast<const float2*>(bias)[sub];
    float2 o;
    o.x = fmaf(di, a.x, b.x);
    o.y = fmaf(di, a.y, b.y);
    reinterpret_cast<float2*>(out)[(size_t)i * 32 + sub] = o;
}

// ---------------- BN stats over f16 t ----------------
__global__ __launch_bounds__(256) void k_stats(const __half2* __restrict__ X2,
                                               float* __restrict__ S, int N) {
    int cp = threadIdx.x & 63;
    int hr = threadIdx.x >> 6;
    int rend = min(N, (int)(blockIdx.x + 1) * 256);
    float2 s = make_float2(0.f, 0.f), q = make_float2(0.f, 0.f);
    for (int r = blockIdx.x * 256 + hr; r < rend; r += 4) {
        float2 v = __half22float2(X2[(size_t)r * 64 + cp]);
        s.x += v.x; s.y += v.y;
        q.x += v.x * v.x; q.y += v.y * v.y;
    }
    __shared__ float ls[4][64][2], lq[4][64][2];
    ls[hr][cp][0] = s.x; ls[hr][cp][1] = s.y;
    lq[hr][cp][0] = q.x; lq[hr][cp][1] = q.y;
    __syncthreads();
    if (hr == 0) {
#pragma unroll
        for (int j = 1; j < 4; j++) {
            s.x += ls[j][cp][0]; s.y += ls[j][cp][1];
            q.x += lq[j][cp][0]; q.y += lq[j][cp][1];
        }
        atomicAdd(&S[2 * cp], s.x);
        atomicAdd(&S[2 * cp + 1], s.y);
        atomicAdd(&S[128 + 2 * cp], q.x);
        atomicAdd(&S[128 + 2 * cp + 1], q.y);
    }
}

// ---------------- launch ----------------
extern "C" void kernel_launch(void* const* d_in, const int* in_sizes, int n_in,
                              void* d_out, int out_size, void* d_ws, size_t ws_size,
                              hipStream_t stream) {
    const float* x   = (const float*)d_in[0];
    const int*   ew  = (const int*)d_in[1];
    const float* W1  = (const float*)d_in[2];
    const float* b1  = (const float*)d_in[3];
    const float* g1  = (const float*)d_in[4];
    const float* be1 = (const float*)d_in[5];
    const float* W2  = (const float*)d_in[6];
    const float* b2  = (const float*)d_in[7];
    const float* g2  = (const float*)d_in[8];
    const float* be2 = (const float*)d_in[9];
    const float* W3  = (const float*)d_in[10];
    const float* b3  = (const float*)d_in[11];
    const int N = in_sizes[0] / 128;
    const int E = in_sizes[1] / 2;
    const int NB = (N + 255) >> 8;

    char* w = (char*)d_ws;
    size_t off = 0;
    auto alloc = [&](size_t bytes) -> char* {
        char* p = w + off;
        off = (off + bytes + 255) & ~(size_t)255;
        return p;
    };
    int*    col   = (int*)alloc((size_t)E * 4);
    int2*   be    = (int2*)alloc((size_t)E * 8);
    int*    rp    = (int*)alloc((size_t)(N + 1) * 4);
    float*  dinv  = (float*)alloc((size_t)N * 4);
    float*  S1    = (float*)alloc(1024);
    float*  S2    = (float*)alloc(1024);
    int*    flag  = (int*)alloc(256);
    int*    bsize = (int*)alloc(257 * 4);
    int*    bbase = (int*)alloc(257 * 4);
    int*    bcur  = (int*)alloc(257 * 4);
    __half* h     = (__half*)alloc((size_t)N * 128 * 2);
    __half* t     = (__half*)alloc((size_t)N * 128 * 2);
    (void)ws_size; (void)n_in; (void)out_size;

    const int gM = (N + 63) / 64;
    const int gA = (N + 3) / 4;
    const int gA8 = (N + 7) / 8;
    const int gS = (N + 255) / 256;
    const int PB = 128;
    const int chunk = (E + PB - 1) / PB;
    const float invN = 1.0f / (float)N;

    hipMemsetAsync(bsize, 0, 257 * 4, stream);
    hipMemsetAsync(S1, 0, 1024, stream);
    hipMemsetAsync(S2, 0, 1024, stream);
    k_detect<<<1, 256, 0, stream>>>(ew, flag);
    k_bhist<<<PB, 256, 0, stream>>>(ew, flag, bsize, E, NB, chunk);
    k_bscan<<<1, 256, 0, stream>>>(bsize, bbase, bcur, NB);
    k_part<<<PB, 256, 0, stream>>>(ew, flag, bcur, be, E, NB, chunk);
    k_bdegscan<<<NB, 256, 0, stream>>>(be, bbase, rp, dinv, N, NB);
    k_fillb<<<NB, 256, 0, stream>>>(be, bbase, rp, col, N);

    // layer 1
    k_mmf<128, false, true><<<gM, 256, 0, stream>>>(x, W1, h, dinv, S1, g1, be1, N, invN);
    k_agg128<<<gA, 256, 0, stream>>>((const __half2*)h, rp, col, dinv, b1, (__half2*)t, N);
    k_stats<<<gS, 256, 0, stream>>>((const __half2*)t, S1, N);

    // layer 2 (BN1+ReLU fused into A-fragment load)
    k_mmf<128, true, false><<<gM, 256, 0, stream>>>(t, W2, h, dinv, S1, g1, be1, N, invN);
    k_agg128<<<gA, 256, 0, stream>>>((const __half2*)h, rp, col, dinv, b2, (__half2*)t, N);
    k_stats<<<gS, 256, 0, stream>>>((const __half2*)t, S2, N);

    // layer 3 (BN2+ReLU fused, D_OUT = 64, straight to d_out)
    k_mmf<64, true, false><<<gM, 256, 0, stream>>>(t, W3, h, dinv, S2, g2, be2, N, invN);
    k_agg64<<<gA8, 256, 0, stream>>>((const __half2*)h, rp, col, dinv, b3, (float*)d_out, N);
}